// Round 4
// baseline (653.321 us; speedup 1.0000x reference)
//
#include <hip/hip_runtime.h>

#define D_ 8
#define B_ 32
#define PRE_ 1024
#define POST_ 1024

// exp(-1/10), exp(-1/20), exp(-1/15)
#define ALPHA_P 0.90483741803595952f
#define ALPHA_D 0.95122942450071400f
#define ALPHA_X 0.93550698503161731f

#define BCHUNK 4                          // b values per main block
#define NBC    (B_ / BCHUNK)              // 8 b-chunks
#define NMAIN  (PRE_ * NBC)               // 8192 main blocks
#define NFILT  (((D_*B_*PRE_)/4 + 2*((B_*POST_)/4)) / 256)   // 320 filter blocks

typedef float f32x4 __attribute__((ext_vector_type(4)));

// Main blocks (bid < NMAIN): e = bid >> 3, bc = bid & 7.
//   Same-e blocks are CONSECUTIVE in dispatch order -> co-resident -> dmap[.,e,.]
//   is fetched from HBM once and served from L2/L3 for the other 7 blocks.
//   W is read-once (non-temporal load); out/W_new are write-once (non-temporal
//   stores) so the ~400 MB stream doesn't evict the reused dmap/A_p/A_d/wmax.
// __launch_bounds__(256, 8): cap VGPR at 64 so 8 waves/SIMD remain possible —
//   round 3 showed VGPR 104 halves occupancy and costs ~10% duration.
// Tail blocks: elementwise exponential filters.
__global__ __launch_bounds__(256, 8) void clopath_fused(
    const float* __restrict__ W,
    const float* __restrict__ dmap,
    const float* __restrict__ A_p,
    const float* __restrict__ A_d,
    const float* __restrict__ wmax,
    const float* __restrict__ xbar_pre,
    const float* __restrict__ Xd,
    const float* __restrict__ Xpost,
    const float* __restrict__ Vpost,
    const float* __restrict__ u_pot,
    const float* __restrict__ u_dep,
    float* __restrict__ out,       // output 0: copy of W
    float* __restrict__ W_new,     // output 1
    float* __restrict__ xbar_new,  // output 2
    float* __restrict__ u_pot_new, // output 3
    float* __restrict__ u_dep_new) // output 4
{
    const int bid = blockIdx.x;
    const int tid = threadIdx.x;

    if (bid < NMAIN) {
        const int e  = bid >> 3;           // 0..1023 (8 consecutive bids share e)
        const int bc = bid & (NBC - 1);    // 0..7
        const int b0 = bc * BCHUNK;        // first b of this block
        const int o  = tid << 2;           // float4 of POST

        // Stage the 32 block-uniform scalars xbar_pre[d, b0+bi, e], Xd[d, b0+bi, e]
        __shared__ float xb_lds[D_ * BCHUNK];
        __shared__ float xd_lds[D_ * BCHUNK];
        if (tid < D_ * BCHUNK) {
            const int d  = tid >> 2;
            const int bi = tid & (BCHUNK - 1);
            const size_t idx = ((size_t)(d * B_ + b0 + bi)) * PRE_ + e;
            xb_lds[tid] = xbar_pre[idx];
            xd_lds[tid] = Xd[idx];
        }
        __syncthreads();

        // Preload dmap rows and per-(e,o) factors into registers (cached reads —
        // these are the reused arrays we want resident in L2/L3)
        float dmv[D_][4];
        #pragma unroll
        for (int d = 0; d < D_; ++d) {
            f32x4 t = *reinterpret_cast<const f32x4*>(
                dmap + ((size_t)(d * PRE_ + e) * POST_ + o));
            dmv[d][0] = t[0]; dmv[d][1] = t[1]; dmv[d][2] = t[2]; dmv[d][3] = t[3];
        }
        f32x4 ap4 = *reinterpret_cast<const f32x4*>(A_p  + ((size_t)e * POST_ + o));
        f32x4 ad4 = *reinterpret_cast<const f32x4*>(A_d  + ((size_t)e * POST_ + o));
        f32x4 wm4 = *reinterpret_cast<const f32x4*>(wmax + ((size_t)e * POST_ + o));

        #pragma unroll
        for (int bi = 0; bi < BCHUNK; ++bi) {
            const int b = b0 + bi;
            const size_t wi = ((size_t)(b * PRE_ + e)) * POST_ + o;
            const size_t go = (size_t)b * POST_ + o;

            // W is read-once: non-temporal
            f32x4 w4  = __builtin_nontemporal_load(
                            reinterpret_cast<const f32x4*>(W + wi));
            f32x4 xp4 = *reinterpret_cast<const f32x4*>(Xpost + go);
            f32x4 up4 = *reinterpret_cast<const f32x4*>(u_pot + go);
            f32x4 ud4 = *reinterpret_cast<const f32x4*>(u_dep + go);

            float sp[4] = {0.f, 0.f, 0.f, 0.f};
            float sd[4] = {0.f, 0.f, 0.f, 0.f};
            #pragma unroll
            for (int d = 0; d < D_; ++d) {
                const float xb = xb_lds[d * BCHUNK + bi];   // uniform -> broadcast
                const float xd = xd_lds[d * BCHUNK + bi];
                #pragma unroll
                for (int j = 0; j < 4; ++j) {
                    sp[j] = fmaf(xb, dmv[d][j], sp[j]);
                    sd[j] = fmaf(xd, dmv[d][j], sd[j]);
                }
            }

            f32x4 nv;
            #pragma unroll
            for (int j = 0; j < 4; ++j) {
                const float gp = xp4[j] * fmaxf(up4[j], 0.f);  // Xpost * relu(u_pot)
                const float gd = fmaxf(ud4[j], 0.f);           // relu(u_dep)
                float wn = w4[j] + sp[j] * ap4[j] * gp - sd[j] * ad4[j] * gd;
                nv[j] = fminf(wm4[j], fmaxf(wn, 0.f));
            }
            // streaming outputs: non-temporal stores
            __builtin_nontemporal_store(w4, reinterpret_cast<f32x4*>(out   + wi));
            __builtin_nontemporal_store(nv, reinterpret_cast<f32x4*>(W_new + wi));
        }
    } else {
        // ---- filter tail: elementwise exponential filters ----
        const int i = (bid - NMAIN) * 256 + tid;   // float4 index
        const int NX = (D_ * B_ * PRE_) / 4;       // 65536
        const int NU = (B_ * POST_) / 4;           // 8192

        if (i < NX) {
            f32x4 a = *reinterpret_cast<const f32x4*>(xbar_pre + (size_t)i * 4);
            f32x4 b = *reinterpret_cast<const f32x4*>(Xd       + (size_t)i * 4);
            f32x4 r = ALPHA_X * a + (1.0f - ALPHA_X) * b;
            __builtin_nontemporal_store(r, reinterpret_cast<f32x4*>(xbar_new + (size_t)i * 4));
        } else if (i < NX + NU) {
            const int j = i - NX;
            f32x4 a = *reinterpret_cast<const f32x4*>(u_pot + (size_t)j * 4);
            f32x4 b = *reinterpret_cast<const f32x4*>(Vpost + (size_t)j * 4);
            f32x4 r = ALPHA_P * a + (1.0f - ALPHA_P) * b;
            __builtin_nontemporal_store(r, reinterpret_cast<f32x4*>(u_pot_new + (size_t)j * 4));
        } else {
            const int j = i - NX - NU;
            f32x4 a = *reinterpret_cast<const f32x4*>(u_dep + (size_t)j * 4);
            f32x4 b = *reinterpret_cast<const f32x4*>(Vpost + (size_t)j * 4);
            f32x4 r = ALPHA_D * a + (1.0f - ALPHA_D) * b;
            __builtin_nontemporal_store(r, reinterpret_cast<f32x4*>(u_dep_new + (size_t)j * 4));
        }
    }
}

extern "C" void kernel_launch(void* const* d_in, const int* in_sizes, int n_in,
                              void* d_out, int out_size, void* d_ws, size_t ws_size,
                              hipStream_t stream) {
    const float* Xd       = (const float*)d_in[0];
    const float* Xpost    = (const float*)d_in[1];
    const float* Vpost    = (const float*)d_in[2];
    const float* W        = (const float*)d_in[3];
    const float* xbar_pre = (const float*)d_in[4];
    const float* u_pot    = (const float*)d_in[5];
    const float* u_dep    = (const float*)d_in[6];
    const float* dmap     = (const float*)d_in[7];
    const float* A_p      = (const float*)d_in[8];
    const float* A_d      = (const float*)d_in[9];
    const float* wmax     = (const float*)d_in[10];

    float* out        = (float*)d_out;
    float* W_new      = out + (size_t)B_ * PRE_ * POST_;
    float* xbar_new   = W_new + (size_t)B_ * PRE_ * POST_;
    float* u_pot_new  = xbar_new + (size_t)D_ * B_ * PRE_;
    float* u_dep_new  = u_pot_new + (size_t)B_ * POST_;

    clopath_fused<<<NMAIN + NFILT, 256, 0, stream>>>(
        W, dmap, A_p, A_d, wmax, xbar_pre, Xd, Xpost, Vpost, u_pot, u_dep,
        out, W_new, xbar_new, u_pot_new, u_dep_new);
}

// Round 5
// 199.302 us; speedup vs baseline: 3.2780x; 3.2780x over previous
//
#include <hip/hip_runtime.h>

#define D_ 8
#define B_ 32
#define PRE_ 1024
#define POST_ 1024

// exp(-1/10), exp(-1/20), exp(-1/15)
#define ALPHA_P 0.90483741803595952f
#define ALPHA_D 0.95122942450071400f
#define ALPHA_X 0.93550698503161731f

#define BCHUNK 4                          // b values per main block
#define NBC    (B_ / BCHUNK)              // 8 b-chunks
#define NMAIN  (PRE_ * NBC)               // 8192 main blocks
#define NFILT  (((D_*B_*PRE_)/4 + 2*((B_*POST_)/4)) / 256)   // 320 filter blocks

typedef float f32x4 __attribute__((ext_vector_type(4)));

// Main blocks (bid < NMAIN): e = bid >> 3, bc = bid & 7.
//   8 same-e blocks are CONSECUTIVE in dispatch order -> co-resident -> dmap[.,e,.]
//   fetched from HBM once, L2/L3 serve the rest (round 3 measured FETCH 160 MB).
//   W read-once via NT load; out/W_new written NT so the ~400 MB stream doesn't
//   evict dmap/A_p/A_d/wmax.
// __launch_bounds__(256, 4): VGPR cap 128 — natural use is ~60-70. Round 4
//   proved (256,8)->32 VGPR causes scratch spills (WRITE 263MB -> 1.4GB, 4.6x dur).
__global__ __launch_bounds__(256, 4) void clopath_fused(
    const float* __restrict__ W,
    const float* __restrict__ dmap,
    const float* __restrict__ A_p,
    const float* __restrict__ A_d,
    const float* __restrict__ wmax,
    const float* __restrict__ xbar_pre,
    const float* __restrict__ Xd,
    const float* __restrict__ Xpost,
    const float* __restrict__ Vpost,
    const float* __restrict__ u_pot,
    const float* __restrict__ u_dep,
    float* __restrict__ out,       // output 0: copy of W
    float* __restrict__ W_new,     // output 1
    float* __restrict__ xbar_new,  // output 2
    float* __restrict__ u_pot_new, // output 3
    float* __restrict__ u_dep_new) // output 4
{
    const int bid = blockIdx.x;
    const int tid = threadIdx.x;

    if (bid < NMAIN) {
        const int e  = bid >> 3;           // 0..1023 (8 consecutive bids share e)
        const int bc = bid & (NBC - 1);    // 0..7
        const int b0 = bc * BCHUNK;        // first b of this block
        const int o  = tid << 2;           // float4 of POST

        // Stage the 32 block-uniform scalars xbar_pre[d, b0+bi, e], Xd[d, b0+bi, e]
        __shared__ float xb_lds[D_ * BCHUNK];
        __shared__ float xd_lds[D_ * BCHUNK];
        if (tid < D_ * BCHUNK) {
            const int d  = tid >> 2;
            const int bi = tid & (BCHUNK - 1);
            const size_t idx = ((size_t)(d * B_ + b0 + bi)) * PRE_ + e;
            xb_lds[tid] = xbar_pre[idx];
            xd_lds[tid] = Xd[idx];
        }
        __syncthreads();

        // Preload dmap rows and per-(e,o) factors (cached reads — these are the
        // reused arrays we want resident in L2/L3)
        float dmv[D_][4];
        #pragma unroll
        for (int d = 0; d < D_; ++d) {
            f32x4 t = *reinterpret_cast<const f32x4*>(
                dmap + ((size_t)(d * PRE_ + e) * POST_ + o));
            dmv[d][0] = t[0]; dmv[d][1] = t[1]; dmv[d][2] = t[2]; dmv[d][3] = t[3];
        }
        f32x4 ap4 = *reinterpret_cast<const f32x4*>(A_p  + ((size_t)e * POST_ + o));
        f32x4 ad4 = *reinterpret_cast<const f32x4*>(A_d  + ((size_t)e * POST_ + o));
        f32x4 wm4 = *reinterpret_cast<const f32x4*>(wmax + ((size_t)e * POST_ + o));

        #pragma unroll
        for (int bi = 0; bi < BCHUNK; ++bi) {
            const int b = b0 + bi;
            const size_t wi = ((size_t)(b * PRE_ + e)) * POST_ + o;
            const size_t go = (size_t)b * POST_ + o;

            // W is read-once: non-temporal
            f32x4 w4  = __builtin_nontemporal_load(
                            reinterpret_cast<const f32x4*>(W + wi));
            f32x4 xp4 = *reinterpret_cast<const f32x4*>(Xpost + go);
            f32x4 up4 = *reinterpret_cast<const f32x4*>(u_pot + go);
            f32x4 ud4 = *reinterpret_cast<const f32x4*>(u_dep + go);

            float sp[4] = {0.f, 0.f, 0.f, 0.f};
            float sd[4] = {0.f, 0.f, 0.f, 0.f};
            #pragma unroll
            for (int d = 0; d < D_; ++d) {
                const float xb = xb_lds[d * BCHUNK + bi];   // uniform -> broadcast
                const float xd = xd_lds[d * BCHUNK + bi];
                #pragma unroll
                for (int j = 0; j < 4; ++j) {
                    sp[j] = fmaf(xb, dmv[d][j], sp[j]);
                    sd[j] = fmaf(xd, dmv[d][j], sd[j]);
                }
            }

            f32x4 nv;
            #pragma unroll
            for (int j = 0; j < 4; ++j) {
                const float gp = xp4[j] * fmaxf(up4[j], 0.f);  // Xpost * relu(u_pot)
                const float gd = fmaxf(ud4[j], 0.f);           // relu(u_dep)
                float wn = w4[j] + sp[j] * ap4[j] * gp - sd[j] * ad4[j] * gd;
                nv[j] = fminf(wm4[j], fmaxf(wn, 0.f));
            }
            // streaming outputs: non-temporal stores
            __builtin_nontemporal_store(w4, reinterpret_cast<f32x4*>(out   + wi));
            __builtin_nontemporal_store(nv, reinterpret_cast<f32x4*>(W_new + wi));
        }
    } else {
        // ---- filter tail: elementwise exponential filters ----
        const int i = (bid - NMAIN) * 256 + tid;   // float4 index
        const int NX = (D_ * B_ * PRE_) / 4;       // 65536
        const int NU = (B_ * POST_) / 4;           // 8192

        if (i < NX) {
            f32x4 a = *reinterpret_cast<const f32x4*>(xbar_pre + (size_t)i * 4);
            f32x4 b = *reinterpret_cast<const f32x4*>(Xd       + (size_t)i * 4);
            f32x4 r = ALPHA_X * a + (1.0f - ALPHA_X) * b;
            __builtin_nontemporal_store(r, reinterpret_cast<f32x4*>(xbar_new + (size_t)i * 4));
        } else if (i < NX + NU) {
            const int j = i - NX;
            f32x4 a = *reinterpret_cast<const f32x4*>(u_pot + (size_t)j * 4);
            f32x4 b = *reinterpret_cast<const f32x4*>(Vpost + (size_t)j * 4);
            f32x4 r = ALPHA_P * a + (1.0f - ALPHA_P) * b;
            __builtin_nontemporal_store(r, reinterpret_cast<f32x4*>(u_pot_new + (size_t)j * 4));
        } else {
            const int j = i - NX - NU;
            f32x4 a = *reinterpret_cast<const f32x4*>(u_dep + (size_t)j * 4);
            f32x4 b = *reinterpret_cast<const f32x4*>(Vpost + (size_t)j * 4);
            f32x4 r = ALPHA_D * a + (1.0f - ALPHA_D) * b;
            __builtin_nontemporal_store(r, reinterpret_cast<f32x4*>(u_dep_new + (size_t)j * 4));
        }
    }
}

extern "C" void kernel_launch(void* const* d_in, const int* in_sizes, int n_in,
                              void* d_out, int out_size, void* d_ws, size_t ws_size,
                              hipStream_t stream) {
    const float* Xd       = (const float*)d_in[0];
    const float* Xpost    = (const float*)d_in[1];
    const float* Vpost    = (const float*)d_in[2];
    const float* W        = (const float*)d_in[3];
    const float* xbar_pre = (const float*)d_in[4];
    const float* u_pot    = (const float*)d_in[5];
    const float* u_dep    = (const float*)d_in[6];
    const float* dmap     = (const float*)d_in[7];
    const float* A_p      = (const float*)d_in[8];
    const float* A_d      = (const float*)d_in[9];
    const float* wmax     = (const float*)d_in[10];

    float* out        = (float*)d_out;
    float* W_new      = out + (size_t)B_ * PRE_ * POST_;
    float* xbar_new   = W_new + (size_t)B_ * PRE_ * POST_;
    float* u_pot_new  = xbar_new + (size_t)D_ * B_ * PRE_;
    float* u_dep_new  = u_pot_new + (size_t)B_ * POST_;

    clopath_fused<<<NMAIN + NFILT, 256, 0, stream>>>(
        W, dmap, A_p, A_d, wmax, xbar_pre, Xd, Xpost, Vpost, u_pot, u_dep,
        out, W_new, xbar_new, u_pot_new, u_dep_new);
}

// Round 6
// 106.515 us; speedup vs baseline: 6.1336x; 1.8711x over previous
//
#include <hip/hip_runtime.h>

#define D_ 8
#define B_ 32
#define PRE_ 1024
#define POST_ 1024

// exp(-1/10), exp(-1/20), exp(-1/15)
#define ALPHA_P 0.90483741803595952f
#define ALPHA_D 0.95122942450071400f
#define ALPHA_X 0.93550698503161731f

#define NMAIN PRE_                                            // 1024 main blocks
#define NFILT (((D_*B_*PRE_)/4 + 2*((B_*POST_)/4)) / 256)     // 320 filter blocks

typedef float f32x4 __attribute__((ext_vector_type(4)));
typedef float f32x2 __attribute__((ext_vector_type(2)));

// One block per e, all 32 b per block:
//   - dmap[.,e,.] (32 KB) staged in LDS once -> reused 32x, NO cache reliance.
//   - xbar/Xd scalars staged as interleaved (xb,xd) pairs -> one b64 broadcast per d.
//   - 1024 blocks == 4/CU capacity at VGPR<=64 -> whole grid co-resident, no drift.
//   - W NT-loaded (read-once) with 1-deep prefetch; out/W_new NT-stored.
// VGPR discipline (round 4/5 lessons): (256,8)->32 VGPR = disaster spills;
//   (256,4)->64 VGPR cap; dmv moved to LDS so natural use ~55-60 fits WITHOUT spill.
//   Spill check: WRITE_SIZE must stay ~263 MB.
__global__ __launch_bounds__(256, 4) void clopath_fused(
    const float* __restrict__ W,
    const float* __restrict__ dmap,
    const float* __restrict__ A_p,
    const float* __restrict__ A_d,
    const float* __restrict__ wmax,
    const float* __restrict__ xbar_pre,
    const float* __restrict__ Xd,
    const float* __restrict__ Xpost,
    const float* __restrict__ Vpost,
    const float* __restrict__ u_pot,
    const float* __restrict__ u_dep,
    float* __restrict__ out,       // output 0: copy of W
    float* __restrict__ W_new,     // output 1
    float* __restrict__ xbar_new,  // output 2
    float* __restrict__ u_pot_new, // output 3
    float* __restrict__ u_dep_new) // output 4
{
    const int bid = blockIdx.x;
    const int tid = threadIdx.x;

    if (bid < NMAIN) {
        const int e = bid;                 // one block per e
        const int o = tid << 2;            // this thread's float4 of POST

        __shared__ float dm_lds[D_ * POST_];   // 32 KB: dmap e-slice
        __shared__ float xbd_lds[B_ * D_ * 2]; // 2 KB: interleaved (xb, xd) per (b,d)

        // Stage (xb, xd) pairs: t -> (b = t>>3, d = t&7)
        {
            const int d = tid & 7;
            const int b = tid >> 3;
            const size_t idx = ((size_t)(d * B_ + b)) * PRE_ + e;
            f32x2 p;
            p.x = xbar_pre[idx];
            p.y = Xd[idx];
            *reinterpret_cast<f32x2*>(&xbd_lds[(b * D_ + d) * 2]) = p;
        }
        // Stage dmap e-slice: thread t loads its own 4 columns for each d (coalesced)
        #pragma unroll
        for (int d = 0; d < D_; ++d) {
            *reinterpret_cast<f32x4*>(&dm_lds[d * POST_ + o]) =
                *reinterpret_cast<const f32x4*>(
                    dmap + ((size_t)(d * PRE_ + e)) * POST_ + o);
        }
        __syncthreads();

        const f32x4 ap4 = *reinterpret_cast<const f32x4*>(A_p  + (size_t)e * POST_ + o);
        const f32x4 ad4 = *reinterpret_cast<const f32x4*>(A_d  + (size_t)e * POST_ + o);
        const f32x4 wm4 = *reinterpret_cast<const f32x4*>(wmax + (size_t)e * POST_ + o);

        // W row stride over b is PRE_*POST_; prefetch b=0
        size_t wi_nxt = (size_t)e * POST_ + o;
        f32x4 w_nxt = __builtin_nontemporal_load(
                          reinterpret_cast<const f32x4*>(W + wi_nxt));

        #pragma unroll 1
        for (int b = 0; b < B_; ++b) {
            const f32x4 w4 = w_nxt;
            const size_t wi = wi_nxt;
            if (b < B_ - 1) {   // uniform branch; 1-deep W prefetch
                wi_nxt += (size_t)PRE_ * POST_;
                w_nxt = __builtin_nontemporal_load(
                            reinterpret_cast<const f32x4*>(W + wi_nxt));
            }

            const size_t go = (size_t)b * POST_ + o;
            const f32x4 xp4 = *reinterpret_cast<const f32x4*>(Xpost + go);
            const f32x4 up4 = *reinterpret_cast<const f32x4*>(u_pot + go);
            const f32x4 ud4 = *reinterpret_cast<const f32x4*>(u_dep + go);

            f32x4 sp = {0.f, 0.f, 0.f, 0.f};
            f32x4 sd = {0.f, 0.f, 0.f, 0.f};
            #pragma unroll
            for (int d = 0; d < D_; ++d) {
                // uniform-address b64 broadcast: (xb, xd) for this (b,d)
                const f32x2 xbd = *reinterpret_cast<const f32x2*>(
                                      &xbd_lds[(b * D_ + d) * 2]);
                // per-thread contiguous b128 read of dmap columns
                const f32x4 dm = *reinterpret_cast<const f32x4*>(
                                      &dm_lds[d * POST_ + o]);
                #pragma unroll
                for (int j = 0; j < 4; ++j) {
                    sp[j] = fmaf(xbd.x, dm[j], sp[j]);
                    sd[j] = fmaf(xbd.y, dm[j], sd[j]);
                }
            }

            f32x4 nv;
            #pragma unroll
            for (int j = 0; j < 4; ++j) {
                const float gp = xp4[j] * fmaxf(up4[j], 0.f);  // Xpost * relu(u_pot)
                const float gd = fmaxf(ud4[j], 0.f);           // relu(u_dep)
                float wn = w4[j] + sp[j] * ap4[j] * gp - sd[j] * ad4[j] * gd;
                nv[j] = fminf(wm4[j], fmaxf(wn, 0.f));
            }
            __builtin_nontemporal_store(w4, reinterpret_cast<f32x4*>(out   + wi));
            __builtin_nontemporal_store(nv, reinterpret_cast<f32x4*>(W_new + wi));
        }
    } else {
        // ---- filter tail: elementwise exponential filters ----
        const int i = (bid - NMAIN) * 256 + tid;   // float4 index
        const int NX = (D_ * B_ * PRE_) / 4;       // 65536
        const int NU = (B_ * POST_) / 4;           // 8192

        if (i < NX) {
            f32x4 a = *reinterpret_cast<const f32x4*>(xbar_pre + (size_t)i * 4);
            f32x4 b = *reinterpret_cast<const f32x4*>(Xd       + (size_t)i * 4);
            f32x4 r = ALPHA_X * a + (1.0f - ALPHA_X) * b;
            __builtin_nontemporal_store(r, reinterpret_cast<f32x4*>(xbar_new + (size_t)i * 4));
        } else if (i < NX + NU) {
            const int j = i - NX;
            f32x4 a = *reinterpret_cast<const f32x4*>(u_pot + (size_t)j * 4);
            f32x4 b = *reinterpret_cast<const f32x4*>(Vpost + (size_t)j * 4);
            f32x4 r = ALPHA_P * a + (1.0f - ALPHA_P) * b;
            __builtin_nontemporal_store(r, reinterpret_cast<f32x4*>(u_pot_new + (size_t)j * 4));
        } else {
            const int j = i - NX - NU;
            f32x4 a = *reinterpret_cast<const f32x4*>(u_dep + (size_t)j * 4);
            f32x4 b = *reinterpret_cast<const f32x4*>(Vpost + (size_t)j * 4);
            f32x4 r = ALPHA_D * a + (1.0f - ALPHA_D) * b;
            __builtin_nontemporal_store(r, reinterpret_cast<f32x4*>(u_dep_new + (size_t)j * 4));
        }
    }
}

extern "C" void kernel_launch(void* const* d_in, const int* in_sizes, int n_in,
                              void* d_out, int out_size, void* d_ws, size_t ws_size,
                              hipStream_t stream) {
    const float* Xd       = (const float*)d_in[0];
    const float* Xpost    = (const float*)d_in[1];
    const float* Vpost    = (const float*)d_in[2];
    const float* W        = (const float*)d_in[3];
    const float* xbar_pre = (const float*)d_in[4];
    const float* u_pot    = (const float*)d_in[5];
    const float* u_dep    = (const float*)d_in[6];
    const float* dmap     = (const float*)d_in[7];
    const float* A_p      = (const float*)d_in[8];
    const float* A_d      = (const float*)d_in[9];
    const float* wmax     = (const float*)d_in[10];

    float* out        = (float*)d_out;
    float* W_new      = out + (size_t)B_ * PRE_ * POST_;
    float* xbar_new   = W_new + (size_t)B_ * PRE_ * POST_;
    float* u_pot_new  = xbar_new + (size_t)D_ * B_ * PRE_;
    float* u_dep_new  = u_pot_new + (size_t)B_ * POST_;

    clopath_fused<<<NMAIN + NFILT, 256, 0, stream>>>(
        W, dmap, A_p, A_d, wmax, xbar_pre, Xd, Xpost, Vpost, u_pot, u_dep,
        out, W_new, xbar_new, u_pot_new, u_dep_new);
}